// Round 2
// baseline (248.262 us; speedup 1.0000x reference)
//
#include <hip/hip_runtime.h>
#include <hip/hip_bf16.h>
#include <stdint.h>

#define DI __device__ __forceinline__

typedef float f32x4 __attribute__((ext_vector_type(4)));
typedef short bf16x8 __attribute__((ext_vector_type(8)));

constexpr int BB = 8192, TT = 128, DD = 16, HH = 32;
constexpr float kEPS = 1e-5f;
constexpr float kLOG2E = 1.44269504088896340736f;

// ---------------- helpers ----------------
DI float rcpf_(float x) { return __builtin_amdgcn_rcpf(x); }
DI float exp2f_(float x) { return __builtin_amdgcn_exp2f(x); }
// acc already = -u*log2e  ->  sigmoid(u)
DI float sig_pre(float acc) { return rcpf_(1.0f + exp2f_(acc)); }
// plain sigmoid(x)
DI float sigm(float x) { return rcpf_(1.0f + exp2f_(-kLOG2E * x)); }

DI uint32_t cvtpk(float lo, float hi) {
  uint32_t r;
  asm("v_cvt_pk_bf16_f32 %0, %1, %2" : "=v"(r) : "v"(lo), "v"(hi));
  return r;
}

DI f32x4 mfma_(bf16x8 a, bf16x8 b, f32x4 c) {
  return __builtin_amdgcn_mfma_f32_16x16x32_bf16(a, b, c, 0, 0, 0);
}

// ---------------- weight prep (per net) ----------------
// ws per-net block (64 KiB stride), bf16 area (uint16 offsets):
//   0: Wih0[96][32]  3072: Whh0  6144: Wih1  9216: Whh1
//   12288: embW[32][32] (BN-folded)  13312: outW[16][32] (zero-padded)
// k within each row is permuted in pairs: slot 2m = logical k=m,
// slot 2m+1 = logical k=m+16.
// f32 bias area at byte 28672: brz0[64] bin0[32] bhn0[32]
//   brz1[64] bin1[32] bhn1[32] bias_e[32] outB[16]
__global__ void prep_net(const float* Wih0, const float* Whh0,
                         const float* bih0, const float* bhh0,
                         const float* Wih1, const float* Whh1,
                         const float* bih1, const float* bhh1,
                         const float* embW, const float* embB,
                         const float* bng, const float* bnb,
                         const float* bnm, const float* bnv,
                         const float* outW, const float* outB,
                         int outDim, uint8_t* wsbase) {
  int tid = threadIdx.x;
  uint16_t* W = (uint16_t*)wsbase;
  float* bias = (float*)(wsbase + 28672);
  auto cvt = [](float f) -> uint16_t {
    union { float f; uint32_t u; } v; v.f = f;
    uint32_t u = v.u;
    return (uint16_t)((u + 0x7FFF + ((u >> 16) & 1)) >> 16);  // RNE
  };
  const float* srcs[4] = {Wih0, Whh0, Wih1, Whh1};
#pragma unroll
  for (int m = 0; m < 4; ++m) {
    const float* src = srcs[m];
    uint16_t* dst = W + m * 3072;
    for (int idx = tid; idx < 3072; idx += 256) {
      int n = idx >> 5, p = idx & 31;
      int k = (p & 1) ? 16 + (p >> 1) : (p >> 1);
      float s = (n < 64) ? -kLOG2E : 2.0f * kLOG2E;
      dst[idx] = cvt(src[n * 32 + k] * s);
    }
  }
  for (int idx = tid; idx < 1024; idx += 256) {
    int n = idx >> 5, p = idx & 31;
    int k = (p & 1) ? 16 + (p >> 1) : (p >> 1);
    float a = bng[n] * rsqrtf(bnv[n] + kEPS);
    (W + 12288)[idx] = cvt(embW[n * 32 + k] * a);
  }
  for (int idx = tid; idx < 512; idx += 256) {
    int n = idx >> 5, p = idx & 31;
    int k = (p & 1) ? 16 + (p >> 1) : (p >> 1);
    float v = (n < outDim) ? outW[n * 32 + k] : 0.0f;
    (W + 13312)[idx] = cvt(v);
  }
  if (tid < 64) {
    bias[tid]       = (bih0[tid] + bhh0[tid]) * (-kLOG2E);
    bias[128 + tid] = (bih1[tid] + bhh1[tid]) * (-kLOG2E);
  }
  if (tid < 32) {
    bias[64 + tid]  = bih0[64 + tid] * (2.0f * kLOG2E);
    bias[96 + tid]  = bhh0[64 + tid] * (2.0f * kLOG2E);
    bias[192 + tid] = bih1[64 + tid] * (2.0f * kLOG2E);
    bias[224 + tid] = bhh1[64 + tid] * (2.0f * kLOG2E);
    float a = bng[tid] * rsqrtf(bnv[tid] + kEPS);
    bias[256 + tid] = a * embB[tid] + bnb[tid] - bnm[tid] * a;
  }
  if (tid < 16) bias[288 + tid] = (tid < outDim) ? outB[tid] : 0.0f;
}

// ---------------- fused RNN + heads (2 waves per group, N-split) ----------
// Block = 128 threads = 2 waves. Wave wh computes h-state cols
// [16*wh, 16*wh+16) of both GRU layers + e-half of the head for one
// 16-row batch group of one net. Waves exchange halves via LDS.
__global__ __launch_bounds__(128) void rnn_fused(
    const float* __restrict__ S, const float* __restrict__ gS,
    const float* __restrict__ hp0, const float* __restrict__ hd0,
    const uint8_t* __restrict__ ws, float* __restrict__ out) {
  const int tid = threadIdx.x;
  const int lane = tid & 63, wh = tid >> 6;     // wh = N-half 0/1
  const int net = blockIdx.x & 1;               // 0 = price, 1 = delta
  const int b0 = (blockIdx.x >> 1) * 16;
  const int c = lane & 15, kg = lane >> 4;      // kg in 0..3

  const uint16_t* W = (const uint16_t*)(ws + net * 65536);
  const float* bias = (const float*)(ws + net * 65536 + 28672);

  __shared__ uint16_t bufs[3][16 * 72];  // 16 rows x 144B stride (k-permuted)

  // B-fragments for this wave's gate tiles (k already permuted in ws)
  auto frag = [&](int base, int tt) -> bf16x8 {
    return *(const bf16x8*)(W + base + (tt * 16 + c) * 32 + kg * 8);
  };
  const int tr = wh, tz = 2 + wh, tn = 4 + wh;
  bf16x8 Wr0i = frag(0, tr),    Wz0i = frag(0, tz),    Wn0i = frag(0, tn);
  bf16x8 Wr0h = frag(3072, tr), Wz0h = frag(3072, tz), Wn0h = frag(3072, tn);
  bf16x8 Wr1i = frag(6144, tr), Wz1i = frag(6144, tz), Wn1i = frag(6144, tn);
  bf16x8 Wr1h = frag(9216, tr), Wz1h = frag(9216, tz), Wn1h = frag(9216, tn);
  bf16x8 Wembf = frag(12288, wh);
  bf16x8 Woutf = *(const bf16x8*)(W + 13312 + c * 32 + kg * 8);

  const float br0 = bias[wh * 16 + c],        bz0 = bias[32 + wh * 16 + c];
  const float bi0 = bias[64 + wh * 16 + c],   bh0 = bias[96 + wh * 16 + c];
  const float br1 = bias[128 + wh * 16 + c],  bz1 = bias[160 + wh * 16 + c];
  const float bi1 = bias[192 + wh * 16 + c],  bh1 = bias[224 + wh * 16 + c];
  const float bev = bias[256 + wh * 16 + c];
  const float outbv = bias[288 + c];

  // initial hidden states
  const float* hsrc = net ? hd0 : hp0;
  // A-fragments (full k=32), built straight from global in permuted order
  auto loadA = [&](const float* row) -> bf16x8 {
    f32x4 a = *(const f32x4*)(row + 4 * kg);
    f32x4 b = *(const f32x4*)(row + 16 + 4 * kg);
    union { uint32_t u[4]; bf16x8 v; } t;
#pragma unroll
    for (int j = 0; j < 4; ++j) t.u[j] = cvtpk(a[j], b[j]);
    return t.v;
  };
  bf16x8 h0f = loadA(hsrc + (size_t)(b0 + c) * HH);
  bf16x8 h1f = loadA(hsrc + ((size_t)BB + b0 + c) * HH);
  // C-layout own-half values (row 4kg+r, col 16wh+c)
  float h0c[4], h1c[4];
#pragma unroll
  for (int r = 0; r < 4; ++r) {
    h0c[r] = hsrc[(size_t)(b0 + 4 * kg + r) * HH + 16 * wh + c];
    h1c[r] = hsrc[((size_t)BB + b0 + 4 * kg + r) * HH + 16 * wh + c];
  }

  // exchange: write own half (bf16, permuted slot 2c+wh), barrier, read full
  auto exchange = [&](uint16_t* buf, const float v[4]) -> bf16x8 {
#pragma unroll
    for (int r = 0; r < 4; ++r)
      buf[(4 * kg + r) * 72 + 2 * c + wh] = (uint16_t)cvtpk(v[r], v[r]);
    __syncthreads();
    return *(const bf16x8*)(buf + c * 72 + kg * 8);
  };

  // gate math for one layer-half
  auto gates = [&](f32x4 racc, f32x4 zacc, f32x4 ni, f32x4 nh,
                   float br, float bz, float bi, float bh, float hc[4]) {
#pragma unroll
    for (int r = 0; r < 4; ++r) {
      float rg = sig_pre(racc[r] + br);
      float zg = sig_pre(zacc[r] + bz);
      float w = ni[r] + bi + rg * (nh[r] + bh);
      float n = 1.0f - 2.0f * rcpf_(1.0f + exp2f_(w));
      hc[r] = n + zg * (hc[r] - n);
    }
  };

  // per-lane streaming pointers (walk t downward)
  const float* Sp  = S  + ((size_t)(b0 + c) * TT + (TT - 1)) * DD + kg * 4;
  const float* gSp = gS + (size_t)(b0 + c) * TT + (TT - 1);
  float* po = out + (size_t)(b0 + 4 * kg) * TT + (TT - 1);
  float* od = out + (size_t)BB * TT +
              ((size_t)(b0 + 4 * kg) * TT + (TT - 1)) * DD + c;

  f32x4 sv = *(const f32x4*)Sp;
  float gs = *gSp;
  const f32x4 zero = {0.f, 0.f, 0.f, 0.f};

#pragma unroll 1
  for (int t = TT - 1; t >= 0; --t) {
    // prefetch next timestep's x
    const float* Spn  = t ? Sp - DD : Sp;
    const float* gSpn = t ? gSp - 1 : gSp;
    f32x4 svn = *(const f32x4*)Spn;
    float gsn = *gSpn;

    // x fragment: even slots = S[4kg+j], odd slots = g_S (permuted layout)
    union { uint32_t u[4]; bf16x8 v; } xu;
    xu.u[0] = cvtpk(sv[0], gs); xu.u[1] = cvtpk(sv[1], gs);
    xu.u[2] = cvtpk(sv[2], gs); xu.u[3] = cvtpk(sv[3], gs);
    bf16x8 xf = xu.v;

    // layer 0
    f32x4 racc = mfma_(xf, Wr0i, zero); racc = mfma_(h0f, Wr0h, racc);
    f32x4 zacc = mfma_(xf, Wz0i, zero); zacc = mfma_(h0f, Wz0h, zacc);
    f32x4 ni   = mfma_(xf, Wn0i, zero);
    f32x4 nh   = mfma_(h0f, Wn0h, zero);
    gates(racc, zacc, ni, nh, br0, bz0, bi0, bh0, h0c);
    h0f = exchange(&bufs[0][0], h0c);           // barrier 1

    // layer 1
    racc = mfma_(h0f, Wr1i, zero); racc = mfma_(h1f, Wr1h, racc);
    zacc = mfma_(h0f, Wz1i, zero); zacc = mfma_(h1f, Wz1h, zacc);
    ni   = mfma_(h0f, Wn1i, zero);
    nh   = mfma_(h1f, Wn1h, zero);
    gates(racc, zacc, ni, nh, br1, bz1, bi1, bh1, h1c);
    h1f = exchange(&bufs[1][0], h1c);           // barrier 2

    // head: e = h1 @ embW^T (BN folded) -> SiLU
    f32x4 e = mfma_(h1f, Wembf, zero);
    float es[4];
#pragma unroll
    for (int r = 0; r < 4; ++r) {
      float a = e[r] + bev;
      es[r] = a * sigm(a);
    }
    bf16x8 ef = exchange(&bufs[2][0], es);      // barrier 3

    // out projection: one wave per block does it; the other starts next step
    if (net == 0) {
      if (wh == 0) {
        f32x4 o = mfma_(ef, Woutf, zero);
        if (c == 0) {
#pragma unroll
          for (int r = 0; r < 4; ++r) po[r * TT] = o[r] + outbv;
        }
      }
    } else {
      if (wh == 1) {
        f32x4 o = mfma_(ef, Woutf, zero);
#pragma unroll
        for (int r = 0; r < 4; ++r) od[(size_t)r * TT * DD] = sigm(o[r] + outbv);
      }
    }

    sv = svn; gs = gsn;
    Sp = Spn; gSp = gSpn;
    po -= 1; od -= DD;
  }
}

// ---------------- launch ----------------
extern "C" void kernel_launch(void* const* d_in, const int* in_sizes, int n_in,
                              void* d_out, int out_size, void* d_ws,
                              size_t ws_size, hipStream_t stream) {
  const float* S   = (const float*)d_in[0];
  const float* gS  = (const float*)d_in[1];
  const float* hp0 = (const float*)d_in[5];
  const float* hd0 = (const float*)d_in[6];
  uint8_t* ws = (uint8_t*)d_ws;

  prep_net<<<1, 256, 0, stream>>>(
      (const float*)d_in[7],  (const float*)d_in[8],  (const float*)d_in[9],
      (const float*)d_in[10], (const float*)d_in[11], (const float*)d_in[12],
      (const float*)d_in[13], (const float*)d_in[14], (const float*)d_in[15],
      (const float*)d_in[16], (const float*)d_in[17], (const float*)d_in[18],
      (const float*)d_in[19], (const float*)d_in[20], (const float*)d_in[21],
      (const float*)d_in[22], 1, ws);
  prep_net<<<1, 256, 0, stream>>>(
      (const float*)d_in[23], (const float*)d_in[24], (const float*)d_in[25],
      (const float*)d_in[26], (const float*)d_in[27], (const float*)d_in[28],
      (const float*)d_in[29], (const float*)d_in[30], (const float*)d_in[31],
      (const float*)d_in[32], (const float*)d_in[33], (const float*)d_in[34],
      (const float*)d_in[35], (const float*)d_in[36], (const float*)d_in[37],
      (const float*)d_in[38], 16, ws + 65536);

  rnn_fused<<<dim3((BB / 16) * 2), dim3(128), 0, stream>>>(S, gS, hp0, hd0,
                                                           ws, (float*)d_out);
}

// Round 3
// 187.569 us; speedup vs baseline: 1.3236x; 1.3236x over previous
//
#include <hip/hip_runtime.h>
#include <hip/hip_bf16.h>
#include <stdint.h>

#define DI __device__ __forceinline__

typedef float f32x4 __attribute__((ext_vector_type(4)));
typedef short bf16x8 __attribute__((ext_vector_type(8)));

constexpr int BB = 8192, TT = 128, DD = 16, HH = 32;
constexpr float kEPS = 1e-5f;
constexpr float kLOG2E = 1.44269504088896340736f;

// ---------------- helpers ----------------
DI float rcpf_(float x) { return __builtin_amdgcn_rcpf(x); }
DI float exp2f_(float x) { return __builtin_amdgcn_exp2f(x); }
// acc already = -u*log2e  ->  sigmoid(u)
DI float sig_pre(float acc) { return rcpf_(1.0f + exp2f_(acc)); }
// plain sigmoid(x)
DI float sigm(float x) { return rcpf_(1.0f + exp2f_(-kLOG2E * x)); }

DI uint32_t cvtpk(float lo, float hi) {
  uint32_t r;
  asm("v_cvt_pk_bf16_f32 %0, %1, %2" : "=v"(r) : "v"(lo), "v"(hi));
  return r;
}

DI f32x4 mfma_(bf16x8 a, bf16x8 b, f32x4 c) {
  return __builtin_amdgcn_mfma_f32_16x16x32_bf16(a, b, c, 0, 0, 0);
}

// ---------------- weight prep (per net) ----------------
// Transposed scheme: W tiles are the MFMA *A* operand, state is *B*.
// A-frag: lane l holds A[row=l&15][k=8*(l>>4)+j], natural k order.
// ws per-net block (32 KiB stride):
//   u16[27*512]: 27 tiles (Wih0 r0 r1 z0 z1 n0 n1 | Whh0 ... | Wih1 ... |
//                Whh1 ... | emb e0 e1 | out), each tile = 64 lanes x 8 bf16.
//   f32[304] at byte 27648: 19 bias tiles x 16
//   (L0: r0 r1 z0 z1 i0 i1 h0 h1 | L1: same | e0 e1 | out)
__global__ void prep_net(const float* Wih0, const float* Whh0,
                         const float* bih0, const float* bhh0,
                         const float* Wih1, const float* Whh1,
                         const float* bih1, const float* bhh1,
                         const float* embW, const float* embB,
                         const float* bng, const float* bnb,
                         const float* bnm, const float* bnv,
                         const float* outW, const float* outB,
                         int outDim, uint8_t* wsbase) {
  int tid = threadIdx.x;
  uint16_t* W = (uint16_t*)wsbase;
  float* bias = (float*)(wsbase + 27648);
  auto cvt = [](float f) -> uint16_t {
    union { float f; uint32_t u; } v; v.f = f;
    uint32_t u = v.u;
    return (uint16_t)((u + 0x7FFF + ((u >> 16) & 1)) >> 16);  // RNE
  };
  for (int idx = tid; idx < 27 * 64; idx += 256) {
    int tile = idx >> 6, l = idx & 63, cc = l & 15, gg = l >> 4;
    uint16_t* dst = W + (size_t)idx * 8;
    if (tile < 24) {
      const float* mats[4] = {Wih0, Whh0, Wih1, Whh1};
      const float* src = mats[tile / 6];
      int sub = tile % 6;                   // r0 r1 z0 z1 n0 n1
      int row = sub * 16 + cc;              // rows: r 0-31, z 32-63, n 64-95
      float sc = (sub < 4) ? -kLOG2E : 2.0f * kLOG2E;
#pragma unroll
      for (int j = 0; j < 8; ++j) dst[j] = cvt(src[row * 32 + 8 * gg + j] * sc);
    } else if (tile < 26) {
      int row = (tile - 24) * 16 + cc;
      float a = bng[row] * rsqrtf(bnv[row] + kEPS);
#pragma unroll
      for (int j = 0; j < 8; ++j) dst[j] = cvt(embW[row * 32 + 8 * gg + j] * a);
    } else {
      int rrow = (cc < outDim) ? cc : 0;
      float sc = (cc < outDim) ? 1.0f : 0.0f;
#pragma unroll
      for (int j = 0; j < 8; ++j) dst[j] = cvt(outW[rrow * 32 + 8 * gg + j] * sc);
    }
  }
  for (int idx = tid; idx < 304; idx += 256) {
    int tile = idx >> 4, n = idx & 15;
    float v;
    if (tile < 8) {
      if (tile < 4)      v = (bih0[tile * 16 + n] + bhh0[tile * 16 + n]) * (-kLOG2E);
      else if (tile < 6) v = bih0[64 + (tile - 4) * 16 + n] * (2.0f * kLOG2E);
      else               v = bhh0[64 + (tile - 6) * 16 + n] * (2.0f * kLOG2E);
    } else if (tile < 16) {
      int tt = tile - 8;
      if (tt < 4)        v = (bih1[tt * 16 + n] + bhh1[tt * 16 + n]) * (-kLOG2E);
      else if (tt < 6)   v = bih1[64 + (tt - 4) * 16 + n] * (2.0f * kLOG2E);
      else               v = bhh1[64 + (tt - 6) * 16 + n] * (2.0f * kLOG2E);
    } else if (tile < 18) {
      int nn = (tile - 16) * 16 + n;
      float a = bng[nn] * rsqrtf(bnv[nn] + kEPS);
      v = a * (embB[nn] - bnm[nn]) + bnb[nn];
    } else {
      v = (n < outDim) ? outB[n] : 0.0f;
    }
    bias[idx] = v;
  }
}

// ---------------- fused RNN + heads, software-pipelined ----------------
// 1024 independent waves (16 batch rows x 1 net each), no LDS, no barriers.
// Per iter: L1(t+1) and head(t+1) overlap L0(t)'s latency.
__global__ __launch_bounds__(256, 1) void rnn_fused(
    const float* __restrict__ S, const float* __restrict__ gS,
    const float* __restrict__ hp0, const float* __restrict__ hd0,
    const uint8_t* __restrict__ ws, float* __restrict__ out) {
  const int tid = threadIdx.x, lane = tid & 63, wid = tid >> 6;
  const int net = blockIdx.x & 1;                 // 0 = price, 1 = delta
  const int b0 = (((blockIdx.x >> 1) << 2) + wid) * 16;
  const int c = lane & 15, g = lane >> 4;

  const uint16_t* W = (const uint16_t*)(ws + net * 32768);
  const float* bias = (const float*)(ws + net * 32768 + 27648);

  bf16x8 Wt[27];
#pragma unroll
  for (int tt = 0; tt < 27; ++tt)
    Wt[tt] = *(const bf16x8*)(W + (tt * 64 + lane) * 8);
  f32x4 Bq[19];
#pragma unroll
  for (int tt = 0; tt < 19; ++tt)
    Bq[tt] = *(const f32x4*)(bias + tt * 16 + 4 * g);

  // regroup: gate-layout f32 v[8] (dims {4g+r} and {16+4g+r} for batch c)
  // -> B-frag (lane c+16g' holds dims 8g'..8g'+7), via 8 bpermute + 4 sel.
  const int addr0 = ((lane & 15) | ((lane & 16) << 1)) << 2;
  const int addr1 = addr0 + 64;
  const bool lo32 = lane < 32;
  auto regroup = [&](const float (&v)[8]) -> bf16x8 {
    int P0 = (int)cvtpk(v[0], v[1]), P1 = (int)cvtpk(v[2], v[3]);
    int Q0 = (int)cvtpk(v[4], v[5]), Q1 = (int)cvtpk(v[6], v[7]);
    union { uint32_t u[4]; bf16x8 r; } t;
    int a, b;
    a = __builtin_amdgcn_ds_bpermute(addr0, P0);
    b = __builtin_amdgcn_ds_bpermute(addr0, Q0);
    t.u[0] = lo32 ? a : b;
    a = __builtin_amdgcn_ds_bpermute(addr0, P1);
    b = __builtin_amdgcn_ds_bpermute(addr0, Q1);
    t.u[1] = lo32 ? a : b;
    a = __builtin_amdgcn_ds_bpermute(addr1, P0);
    b = __builtin_amdgcn_ds_bpermute(addr1, Q0);
    t.u[2] = lo32 ? a : b;
    a = __builtin_amdgcn_ds_bpermute(addr1, P1);
    b = __builtin_amdgcn_ds_bpermute(addr1, Q1);
    t.u[3] = lo32 ? a : b;
    return t.r;
  };

  // GRU: biases pre-folded into acc init; weights pre-scaled for exp2 form.
  auto gru = [&](int wih, int whh, int bb, bf16x8 xf, bf16x8 hf,
                 float (&hC)[8]) {
    f32x4 r0 = mfma_(Wt[wih + 0], xf, Bq[bb + 0]); r0 = mfma_(Wt[whh + 0], hf, r0);
    f32x4 r1 = mfma_(Wt[wih + 1], xf, Bq[bb + 1]); r1 = mfma_(Wt[whh + 1], hf, r1);
    f32x4 z0 = mfma_(Wt[wih + 2], xf, Bq[bb + 2]); z0 = mfma_(Wt[whh + 2], hf, z0);
    f32x4 z1 = mfma_(Wt[wih + 3], xf, Bq[bb + 3]); z1 = mfma_(Wt[whh + 3], hf, z1);
    f32x4 ni0 = mfma_(Wt[wih + 4], xf, Bq[bb + 4]);
    f32x4 ni1 = mfma_(Wt[wih + 5], xf, Bq[bb + 5]);
    f32x4 nh0 = mfma_(Wt[whh + 4], hf, Bq[bb + 6]);
    f32x4 nh1 = mfma_(Wt[whh + 5], hf, Bq[bb + 7]);
#pragma unroll
    for (int r = 0; r < 4; ++r) {
      float rg0 = sig_pre(r0[r]), rg1 = sig_pre(r1[r]);
      float zg0 = sig_pre(z0[r]), zg1 = sig_pre(z1[r]);
      float w0 = ni0[r] + rg0 * nh0[r];
      float w1 = ni1[r] + rg1 * nh1[r];
      float n0 = 1.0f - 2.0f * rcpf_(1.0f + exp2f_(w0));
      float n1 = 1.0f - 2.0f * rcpf_(1.0f + exp2f_(w1));
      hC[r]     = n0 + zg0 * (hC[r]     - n0);
      hC[4 + r] = n1 + zg1 * (hC[4 + r] - n1);
    }
  };

  auto head = [&](bf16x8 h1f, int th) {
    f32x4 e0 = mfma_(Wt[24], h1f, Bq[16]);
    f32x4 e1 = mfma_(Wt[25], h1f, Bq[17]);
    float es[8];
#pragma unroll
    for (int r = 0; r < 4; ++r) {
      float a = e0[r], b = e1[r];
      es[r]     = a * sigm(a);
      es[4 + r] = b * sigm(b);
    }
    bf16x8 ef = regroup(es);
    f32x4 o = mfma_(Wt[26], ef, Bq[18]);
    if (net == 0) {
      if (lane < 16) out[(size_t)(b0 + c) * TT + th] = o[0];
    } else {
      f32x4 so;
#pragma unroll
      for (int r = 0; r < 4; ++r) so[r] = sigm(o[r]);
      *(f32x4*)(out + (size_t)BB * TT +
                ((size_t)(b0 + c) * TT + th) * DD + 4 * g) = so;
    }
  };

  // x B-frag: k 0-15 = S dims, k 16-31 = gS broadcast.
  auto mkX = [&](f32x4 sa, f32x4 sb, float gs) -> bf16x8 {
    uint32_t pkg = cvtpk(gs, gs);
    union { uint32_t u[4]; bf16x8 v; } t;
    uint32_t p0 = cvtpk(sa[0], sa[1]), p1 = cvtpk(sa[2], sa[3]);
    uint32_t p2 = cvtpk(sb[0], sb[1]), p3 = cvtpk(sb[2], sb[3]);
    t.u[0] = lo32 ? p0 : pkg;
    t.u[1] = lo32 ? p1 : pkg;
    t.u[2] = lo32 ? p2 : pkg;
    t.u[3] = lo32 ? p3 : pkg;
    return t.v;
  };

  // initial states: gate-layout f32 + B-frags
  const float* hsrc = net ? hd0 : hp0;
  float h0C[8], h1C[8];
#pragma unroll
  for (int r = 0; r < 4; ++r) {
    h0C[r]     = hsrc[(size_t)(b0 + c) * HH + 4 * g + r];
    h0C[4 + r] = hsrc[(size_t)(b0 + c) * HH + 16 + 4 * g + r];
    h1C[r]     = hsrc[((size_t)BB + b0 + c) * HH + 4 * g + r];
    h1C[4 + r] = hsrc[((size_t)BB + b0 + c) * HH + 16 + 4 * g + r];
  }
  auto mkB = [&](const float* row) -> bf16x8 {
    f32x4 a = *(const f32x4*)(row);
    f32x4 b = *(const f32x4*)(row + 4);
    union { uint32_t u[4]; bf16x8 v; } t;
    t.u[0] = cvtpk(a[0], a[1]); t.u[1] = cvtpk(a[2], a[3]);
    t.u[2] = cvtpk(b[0], b[1]); t.u[3] = cvtpk(b[2], b[3]);
    return t.v;
  };
  bf16x8 h0B = mkB(hsrc + (size_t)(b0 + c) * HH + 8 * g);
  bf16x8 h1B = mkB(hsrc + ((size_t)BB + b0 + c) * HH + 8 * g);

  // streaming x pointers (walk t downward); every lane loads 8 S floats
  const float* Sp  = S  + ((size_t)(b0 + c) * TT + (TT - 1)) * DD + 8 * (g & 1);
  const float* gSp = gS + (size_t)(b0 + c) * TT + (TT - 1);

  f32x4 sa = *(const f32x4*)Sp, sb = *(const f32x4*)(Sp + 4);
  float gs = *gSp;
  bf16x8 xB = mkX(sa, sb, gs);

  // prologue: L0 at t = T-1
  gru(0, 6, 0, xB, h0B, h0C);
  h0B = regroup(h0C);

  // prefetch t = T-2
  Sp -= DD; gSp -= 1;
  f32x4 sa2 = *(const f32x4*)Sp, sb2 = *(const f32x4*)(Sp + 4);
  float gs2 = *gSp;

#pragma unroll 1
  for (int t = TT - 2; t >= 0; --t) {
    xB = mkX(sa2, sb2, gs2);
    const float* Spn  = t ? Sp - DD : Sp;
    const float* gSpn = t ? gSp - 1 : gSp;
    sa2 = *(const f32x4*)Spn; sb2 = *(const f32x4*)(Spn + 4);
    gs2 = *gSpn;

    gru(12, 18, 8, h0B, h1B, h1C);   // L1: h1[t+1] (uses old h0B, h1B)
    gru(0, 6, 0, xB, h0B, h0C);      // L0: h0[t]
    h1B = regroup(h1C);
    h0B = regroup(h0C);
    head(h1B, t + 1);

    Sp = Spn; gSp = gSpn;
  }
  // epilogue: h1[0] + head(0)
  gru(12, 18, 8, h0B, h1B, h1C);
  h1B = regroup(h1C);
  head(h1B, 0);
}

// ---------------- launch ----------------
extern "C" void kernel_launch(void* const* d_in, const int* in_sizes, int n_in,
                              void* d_out, int out_size, void* d_ws,
                              size_t ws_size, hipStream_t stream) {
  const float* S   = (const float*)d_in[0];
  const float* gS  = (const float*)d_in[1];
  const float* hp0 = (const float*)d_in[5];
  const float* hd0 = (const float*)d_in[6];
  uint8_t* ws = (uint8_t*)d_ws;

  prep_net<<<1, 256, 0, stream>>>(
      (const float*)d_in[7],  (const float*)d_in[8],  (const float*)d_in[9],
      (const float*)d_in[10], (const float*)d_in[11], (const float*)d_in[12],
      (const float*)d_in[13], (const float*)d_in[14], (const float*)d_in[15],
      (const float*)d_in[16], (const float*)d_in[17], (const float*)d_in[18],
      (const float*)d_in[19], (const float*)d_in[20], (const float*)d_in[21],
      (const float*)d_in[22], 1, ws);
  prep_net<<<1, 256, 0, stream>>>(
      (const float*)d_in[23], (const float*)d_in[24], (const float*)d_in[25],
      (const float*)d_in[26], (const float*)d_in[27], (const float*)d_in[28],
      (const float*)d_in[29], (const float*)d_in[30], (const float*)d_in[31],
      (const float*)d_in[32], (const float*)d_in[33], (const float*)d_in[34],
      (const float*)d_in[35], (const float*)d_in[36], (const float*)d_in[37],
      (const float*)d_in[38], 16, ws + 32768);

  rnn_fused<<<dim3(256), dim3(256), 0, stream>>>(S, gS, hp0, hd0, ws,
                                                 (float*)d_out);
}

// Round 4
// 157.337 us; speedup vs baseline: 1.5779x; 1.1921x over previous
//
#include <hip/hip_runtime.h>
#include <hip/hip_bf16.h>
#include <stdint.h>

#define DI __device__ __forceinline__

typedef float f32x4 __attribute__((ext_vector_type(4)));
typedef short bf16x8 __attribute__((ext_vector_type(8)));

constexpr int BB = 8192, TT = 128, DD = 16, HH = 32;
constexpr float kEPS = 1e-5f;
constexpr float kLOG2E = 1.44269504088896340736f;

// ---------------- helpers ----------------
DI float rcpf_(float x) { return __builtin_amdgcn_rcpf(x); }
DI float exp2f_(float x) { return __builtin_amdgcn_exp2f(x); }
DI float sig_pre(float acc) { return rcpf_(1.0f + exp2f_(acc)); }
DI float sigm(float x) { return rcpf_(1.0f + exp2f_(-kLOG2E * x)); }

DI uint32_t cvtpk(float lo, float hi) {
  uint32_t r;
  asm("v_cvt_pk_bf16_f32 %0, %1, %2" : "=v"(r) : "v"(lo), "v"(hi));
  return r;
}

DI f32x4 mfma_(bf16x8 a, bf16x8 b, f32x4 c) {
  return __builtin_amdgcn_mfma_f32_16x16x32_bf16(a, b, c, 0, 0, 0);
}

// LDS-only barrier: drain LDS ops, do NOT drain vmcnt (keeps the global
// x-prefetch in flight across the barrier).
DI void barrier_lds() {
  asm volatile("s_waitcnt lgkmcnt(0)" ::: "memory");
  __builtin_amdgcn_s_barrier();
  asm volatile("" ::: "memory");
}

union U4 { uint4 q; bf16x8 v; };

// ---------------- weight prep (per net) ----------------
// Transposed scheme: W tiles are the MFMA *A* operand, state is *B*.
// A-frag: lane l holds A[row=l&15][k=8*(l>>4)+j], natural k order.
// ws per-net block (32 KiB stride):
//   u16[27*512]: 27 tiles (Wih0 r0 r1 z0 z1 n0 n1 | Whh0 ... | Wih1 ... |
//                Whh1 ... | emb e0 e1 | out), each tile = 64 lanes x 8 bf16.
//   f32[304] at byte 27648: 19 bias tiles x 16
//   (L0: r0 r1 z0 z1 i0 i1 h0 h1 | L1: same | e0 e1 | out)
__global__ void prep_net(const float* Wih0, const float* Whh0,
                         const float* bih0, const float* bhh0,
                         const float* Wih1, const float* Whh1,
                         const float* bih1, const float* bhh1,
                         const float* embW, const float* embB,
                         const float* bng, const float* bnb,
                         const float* bnm, const float* bnv,
                         const float* outW, const float* outB,
                         int outDim, uint8_t* wsbase) {
  int tid = threadIdx.x;
  uint16_t* W = (uint16_t*)wsbase;
  float* bias = (float*)(wsbase + 27648);
  auto cvt = [](float f) -> uint16_t {
    union { float f; uint32_t u; } v; v.f = f;
    uint32_t u = v.u;
    return (uint16_t)((u + 0x7FFF + ((u >> 16) & 1)) >> 16);  // RNE
  };
  for (int idx = tid; idx < 27 * 64; idx += 256) {
    int tile = idx >> 6, l = idx & 63, cc = l & 15, gg = l >> 4;
    uint16_t* dst = W + (size_t)idx * 8;
    if (tile < 24) {
      const float* mats[4] = {Wih0, Whh0, Wih1, Whh1};
      const float* src = mats[tile / 6];
      int sub = tile % 6;                   // r0 r1 z0 z1 n0 n1
      int row = sub * 16 + cc;              // rows: r 0-31, z 32-63, n 64-95
      float sc = (sub < 4) ? -kLOG2E : 2.0f * kLOG2E;
#pragma unroll
      for (int j = 0; j < 8; ++j) dst[j] = cvt(src[row * 32 + 8 * gg + j] * sc);
    } else if (tile < 26) {
      int row = (tile - 24) * 16 + cc;
      float a = bng[row] * rsqrtf(bnv[row] + kEPS);
#pragma unroll
      for (int j = 0; j < 8; ++j) dst[j] = cvt(embW[row * 32 + 8 * gg + j] * a);
    } else {
      int rrow = (cc < outDim) ? cc : 0;
      float sc = (cc < outDim) ? 1.0f : 0.0f;
#pragma unroll
      for (int j = 0; j < 8; ++j) dst[j] = cvt(outW[rrow * 32 + 8 * gg + j] * sc);
    }
  }
  for (int idx = tid; idx < 304; idx += 256) {
    int tile = idx >> 4, n = idx & 15;
    float v;
    if (tile < 8) {
      if (tile < 4)      v = (bih0[tile * 16 + n] + bhh0[tile * 16 + n]) * (-kLOG2E);
      else if (tile < 6) v = bih0[64 + (tile - 4) * 16 + n] * (2.0f * kLOG2E);
      else               v = bhh0[64 + (tile - 6) * 16 + n] * (2.0f * kLOG2E);
    } else if (tile < 16) {
      int tt = tile - 8;
      if (tt < 4)        v = (bih1[tt * 16 + n] + bhh1[tt * 16 + n]) * (-kLOG2E);
      else if (tt < 6)   v = bih1[64 + (tt - 4) * 16 + n] * (2.0f * kLOG2E);
      else               v = bhh1[64 + (tt - 6) * 16 + n] * (2.0f * kLOG2E);
    } else if (tile < 18) {
      int nn = (tile - 16) * 16 + n;
      float a = bng[nn] * rsqrtf(bnv[nn] + kEPS);
      v = a * (embB[nn] - bnm[nn]) + bnb[nn];
    } else {
      v = (n < outDim) ? outB[n] : 0.0f;
    }
    bias[idx] = v;
  }
}

// ---------------- fused RNN + heads, producer/consumer layer split --------
// Block = 128 threads = 2 waves, one batch group (16 rows) of one net.
// Wave A (wid 0): layer-0 recurrence, writes h0B frag to LDS ring (depth 2).
// Wave B (wid 1): layer-1 + head, consumes h0 one step behind.
// One LDS-only barrier per step; A's global x-prefetch stays in flight.
__global__ __launch_bounds__(128, 2) void rnn_fused(
    const float* __restrict__ S, const float* __restrict__ gS,
    const float* __restrict__ hp0, const float* __restrict__ hd0,
    const uint8_t* __restrict__ ws, float* __restrict__ out) {
  const int tid = threadIdx.x, lane = tid & 63, wid = tid >> 6;
  const int net = blockIdx.x & 1;                 // 0 = price, 1 = delta
  const int b0 = (blockIdx.x >> 1) * 16;
  const int c = lane & 15, g = lane >> 4;

  const uint16_t* W = (const uint16_t*)(ws + net * 32768);
  const float* bias = (const float*)(ws + net * 32768 + 27648);
  const float* hsrc = net ? hd0 : hp0;

  __shared__ uint4 sl[2][64];                     // h0B frag ring, depth 2

  // regroup: gate-layout f32 v[8] (dims {4g+r},{16+4g+r} for batch c)
  // -> B-frag (lane c+16g' holds dims 8g'..8g'+7), 8 bpermute + 4 sel.
  const int addr0 = ((lane & 15) | ((lane & 16) << 1)) << 2;
  const int addr1 = addr0 + 64;
  const bool lo32 = lane < 32;
  auto regroup = [&](const float (&v)[8]) -> bf16x8 {
    int P0 = (int)cvtpk(v[0], v[1]), P1 = (int)cvtpk(v[2], v[3]);
    int Q0 = (int)cvtpk(v[4], v[5]), Q1 = (int)cvtpk(v[6], v[7]);
    union { uint32_t u[4]; bf16x8 r; } t;
    int a, b;
    a = __builtin_amdgcn_ds_bpermute(addr0, P0);
    b = __builtin_amdgcn_ds_bpermute(addr0, Q0);
    t.u[0] = lo32 ? a : b;
    a = __builtin_amdgcn_ds_bpermute(addr0, P1);
    b = __builtin_amdgcn_ds_bpermute(addr0, Q1);
    t.u[1] = lo32 ? a : b;
    a = __builtin_amdgcn_ds_bpermute(addr1, P0);
    b = __builtin_amdgcn_ds_bpermute(addr1, Q0);
    t.u[2] = lo32 ? a : b;
    a = __builtin_amdgcn_ds_bpermute(addr1, P1);
    b = __builtin_amdgcn_ds_bpermute(addr1, Q1);
    t.u[3] = lo32 ? a : b;
    return t.r;
  };

  // GRU: biases pre-folded into acc init; weights pre-scaled for exp2 form.
  auto gruStep = [&](const bf16x8 (&Wi)[6], const bf16x8 (&Wh)[6],
                     const f32x4 (&Bb)[8], bf16x8 xf, bf16x8 hf,
                     float (&hC)[8]) {
    f32x4 r0 = mfma_(Wi[0], xf, Bb[0]); r0 = mfma_(Wh[0], hf, r0);
    f32x4 r1 = mfma_(Wi[1], xf, Bb[1]); r1 = mfma_(Wh[1], hf, r1);
    f32x4 z0 = mfma_(Wi[2], xf, Bb[2]); z0 = mfma_(Wh[2], hf, z0);
    f32x4 z1 = mfma_(Wi[3], xf, Bb[3]); z1 = mfma_(Wh[3], hf, z1);
    f32x4 ni0 = mfma_(Wi[4], xf, Bb[4]);
    f32x4 ni1 = mfma_(Wi[5], xf, Bb[5]);
    f32x4 nh0 = mfma_(Wh[4], hf, Bb[6]);
    f32x4 nh1 = mfma_(Wh[5], hf, Bb[7]);
#pragma unroll
    for (int r = 0; r < 4; ++r) {
      float rg0 = sig_pre(r0[r]), rg1 = sig_pre(r1[r]);
      float zg0 = sig_pre(z0[r]), zg1 = sig_pre(z1[r]);
      float w0 = ni0[r] + rg0 * nh0[r];
      float w1 = ni1[r] + rg1 * nh1[r];
      float n0 = 1.0f - 2.0f * rcpf_(1.0f + exp2f_(w0));
      float n1 = 1.0f - 2.0f * rcpf_(1.0f + exp2f_(w1));
      hC[r]     = n0 + zg0 * (hC[r]     - n0);
      hC[4 + r] = n1 + zg1 * (hC[4 + r] - n1);
    }
  };

  auto mkB = [&](const float* row) -> bf16x8 {
    f32x4 a = *(const f32x4*)(row);
    f32x4 b = *(const f32x4*)(row + 4);
    union { uint32_t u[4]; bf16x8 v; } t;
    t.u[0] = cvtpk(a[0], a[1]); t.u[1] = cvtpk(a[2], a[3]);
    t.u[2] = cvtpk(b[0], b[1]); t.u[3] = cvtpk(b[2], b[3]);
    return t.v;
  };

  if (wid == 0) {
    // ================= wave A: layer-0 recurrence =================
    bf16x8 Wi[6], Wh[6];
#pragma unroll
    for (int t = 0; t < 6; ++t) {
      Wi[t] = *(const bf16x8*)(W + ((0 + t) * 64 + lane) * 8);
      Wh[t] = *(const bf16x8*)(W + ((6 + t) * 64 + lane) * 8);
    }
    f32x4 Bb[8];
#pragma unroll
    for (int t = 0; t < 8; ++t)
      Bb[t] = *(const f32x4*)(bias + t * 16 + 4 * g);

    float h0C[8];
#pragma unroll
    for (int r = 0; r < 4; ++r) {
      h0C[r]     = hsrc[(size_t)(b0 + c) * HH + 4 * g + r];
      h0C[4 + r] = hsrc[(size_t)(b0 + c) * HH + 16 + 4 * g + r];
    }
    bf16x8 h0B = mkB(hsrc + (size_t)(b0 + c) * HH + 8 * g);

    // x B-frag: k 0-15 = S dims, k 16-31 = gS broadcast.
    auto mkX = [&](f32x4 sa, f32x4 sb, float gs) -> bf16x8 {
      uint32_t pkg = cvtpk(gs, gs);
      union { uint32_t u[4]; bf16x8 v; } t;
      uint32_t p0 = cvtpk(sa[0], sa[1]), p1 = cvtpk(sa[2], sa[3]);
      uint32_t p2 = cvtpk(sb[0], sb[1]), p3 = cvtpk(sb[2], sb[3]);
      t.u[0] = lo32 ? p0 : pkg;
      t.u[1] = lo32 ? p1 : pkg;
      t.u[2] = lo32 ? p2 : pkg;
      t.u[3] = lo32 ? p3 : pkg;
      return t.v;
    };

    const float* Sp  = S  + ((size_t)(b0 + c) * TT + (TT - 1)) * DD + 8 * (g & 1);
    const float* gSp = gS + (size_t)(b0 + c) * TT + (TT - 1);
    f32x4 sa = *(const f32x4*)Sp, sb = *(const f32x4*)(Sp + 4);
    float gs = *gSp;

    // t = T-1
    bf16x8 xB = mkX(sa, sb, gs);
    gruStep(Wi, Wh, Bb, xB, h0B, h0C);
    h0B = regroup(h0C);
    { U4 u; u.v = h0B; sl[0][lane] = u.q; }
    // prefetch t = T-2
    Sp -= DD; gSp -= 1;
    sa = *(const f32x4*)Sp; sb = *(const f32x4*)(Sp + 4); gs = *gSp;
    barrier_lds();

#pragma unroll 1
    for (int i = 1; i < TT; ++i) {
      xB = mkX(sa, sb, gs);
      const float* Spn  = (i < TT - 1) ? Sp - DD : Sp;
      const float* gSpn = (i < TT - 1) ? gSp - 1 : gSp;
      sa = *(const f32x4*)Spn; sb = *(const f32x4*)(Spn + 4); gs = *gSpn;
      Sp = Spn; gSp = gSpn;

      gruStep(Wi, Wh, Bb, xB, h0B, h0C);
      h0B = regroup(h0C);
      { U4 u; u.v = h0B; sl[i & 1][lane] = u.q; }
      barrier_lds();
    }
  } else {
    // ================= wave B: layer-1 + heads =================
    bf16x8 Wi[6], Wh[6], We0, We1, Wo;
#pragma unroll
    for (int t = 0; t < 6; ++t) {
      Wi[t] = *(const bf16x8*)(W + ((12 + t) * 64 + lane) * 8);
      Wh[t] = *(const bf16x8*)(W + ((18 + t) * 64 + lane) * 8);
    }
    We0 = *(const bf16x8*)(W + (24 * 64 + lane) * 8);
    We1 = *(const bf16x8*)(W + (25 * 64 + lane) * 8);
    Wo  = *(const bf16x8*)(W + (26 * 64 + lane) * 8);
    f32x4 Bb[8];
#pragma unroll
    for (int t = 0; t < 8; ++t)
      Bb[t] = *(const f32x4*)(bias + (8 + t) * 16 + 4 * g);
    const f32x4 Be0 = *(const f32x4*)(bias + 16 * 16 + 4 * g);
    const f32x4 Be1 = *(const f32x4*)(bias + 17 * 16 + 4 * g);
    const f32x4 Bo  = *(const f32x4*)(bias + 18 * 16 + 4 * g);

    float h1C[8];
#pragma unroll
    for (int r = 0; r < 4; ++r) {
      h1C[r]     = hsrc[((size_t)BB + b0 + c) * HH + 4 * g + r];
      h1C[4 + r] = hsrc[((size_t)BB + b0 + c) * HH + 16 + 4 * g + r];
    }
    bf16x8 h1B = mkB(hsrc + ((size_t)BB + b0 + c) * HH + 8 * g);

    auto head = [&](bf16x8 h1f, int th) {
      f32x4 e0 = mfma_(We0, h1f, Be0);
      f32x4 e1 = mfma_(We1, h1f, Be1);
      float es[8];
#pragma unroll
      for (int r = 0; r < 4; ++r) {
        float a = e0[r], b = e1[r];
        es[r]     = a * sigm(a);
        es[4 + r] = b * sigm(b);
      }
      bf16x8 ef = regroup(es);
      f32x4 o = mfma_(Wo, ef, Bo);
      if (net == 0) {
        if (lane < 16) out[(size_t)(b0 + c) * TT + th] = o[0];
      } else {
        f32x4 so;
#pragma unroll
        for (int r = 0; r < 4; ++r) so[r] = sigm(o[r]);
        *(f32x4*)(out + (size_t)BB * TT +
                  ((size_t)(b0 + c) * TT + th) * DD + 4 * g) = so;
      }
    };

    barrier_lds();
#pragma unroll 1
    for (int i = 1; i < TT; ++i) {
      U4 u; u.q = sl[(i - 1) & 1][lane];
      bf16x8 h0t = u.v;                        // h0(TT - i)
      gruStep(Wi, Wh, Bb, h0t, h1B, h1C);
      h1B = regroup(h1C);
      head(h1B, TT - i);
      barrier_lds();
    }
    // tail: h0(0) is in slot (TT-1)&1 = 1
    U4 u; u.q = sl[1][lane];
    gruStep(Wi, Wh, Bb, u.v, h1B, h1C);
    h1B = regroup(h1C);
    head(h1B, 0);
  }
}

// ---------------- launch ----------------
extern "C" void kernel_launch(void* const* d_in, const int* in_sizes, int n_in,
                              void* d_out, int out_size, void* d_ws,
                              size_t ws_size, hipStream_t stream) {
  const float* S   = (const float*)d_in[0];
  const float* gS  = (const float*)d_in[1];
  const float* hp0 = (const float*)d_in[5];
  const float* hd0 = (const float*)d_in[6];
  uint8_t* ws = (uint8_t*)d_ws;

  prep_net<<<1, 256, 0, stream>>>(
      (const float*)d_in[7],  (const float*)d_in[8],  (const float*)d_in[9],
      (const float*)d_in[10], (const float*)d_in[11], (const float*)d_in[12],
      (const float*)d_in[13], (const float*)d_in[14], (const float*)d_in[15],
      (const float*)d_in[16], (const float*)d_in[17], (const float*)d_in[18],
      (const float*)d_in[19], (const float*)d_in[20], (const float*)d_in[21],
      (const float*)d_in[22], 1, ws);
  prep_net<<<1, 256, 0, stream>>>(
      (const float*)d_in[23], (const float*)d_in[24], (const float*)d_in[25],
      (const float*)d_in[26], (const float*)d_in[27], (const float*)d_in[28],
      (const float*)d_in[29], (const float*)d_in[30], (const float*)d_in[31],
      (const float*)d_in[32], (const float*)d_in[33], (const float*)d_in[34],
      (const float*)d_in[35], (const float*)d_in[36], (const float*)d_in[37],
      (const float*)d_in[38], 16, ws + 32768);

  rnn_fused<<<dim3((BB / 16) * 2), dim3(128), 0, stream>>>(S, gS, hp0, hd0,
                                                           ws, (float*)d_out);
}